// Round 1
// baseline (272.956 us; speedup 1.0000x reference)
//
#include <hip/hip_runtime.h>
#include <hip/hip_bf16.h>

typedef unsigned int u32;
typedef unsigned short ushort_t;
typedef __bf16 bf16x8 __attribute__((ext_vector_type(8)));
typedef float f32x4 __attribute__((ext_vector_type(4)));
typedef unsigned short ushort8 __attribute__((ext_vector_type(8)));

// Problem constants
#define BB 16
#define OO 3
#define TT 8
#define CIN 3
#define IMG 224
#define PP 16
#define DD 768
#define HFD 14            // IMG/P
#define SS 7
#define GM 25088          // B*T*14*14
#define GK 768            // CIN*P*P
#define GN 768            // D

__device__ __forceinline__ ushort_t f2bf(float f) {
    u32 u = __float_as_uint(f);
    u32 r = (u + 0x7FFFu + ((u >> 16) & 1u)) >> 16;
    return (ushort_t)r;
}

__device__ __forceinline__ void load_lds16(const void* g, void* l) {
    __builtin_amdgcn_global_load_lds(
        (const __attribute__((address_space(1))) u32*)g,
        (__attribute__((address_space(3))) u32*)l, 16, 0, 0);
}

// ---------------------------------------------------------------
// Pack x (B,C,T,224,224) fp32 -> A (M,K) bf16, M=(b,t,h,w), K=(c,p,q)
// ---------------------------------------------------------------
__global__ __launch_bounds__(256) void pack_a(const float* __restrict__ x,
                                              ushort_t* __restrict__ Ap) {
    int g = blockIdx.x * 256 + threadIdx.x;     // one thread = 8 consecutive k
    int m = g / 96;                              // 768/8 = 96 chunks per row
    int k0 = (g % 96) * 8;
    int w = m % 14;
    int h = (m / 14) % 14;
    int t = (m / 196) % 8;
    int b = m / 1568;
    int c = k0 >> 8;
    int rem = k0 & 255;
    int p = rem >> 4;
    int q0 = rem & 15;                           // 0 or 8
    const float* src = x + ((((size_t)(b * 3 + c) * 8 + t) * 224 + (h * 16 + p)) * 224
                            + (w * 16 + q0));
    f32x4 f0 = *(const f32x4*)src;
    f32x4 f1 = *(const f32x4*)(src + 4);
    ushort8 r;
    r[0] = f2bf(f0[0]); r[1] = f2bf(f0[1]); r[2] = f2bf(f0[2]); r[3] = f2bf(f0[3]);
    r[4] = f2bf(f1[0]); r[5] = f2bf(f1[1]); r[6] = f2bf(f1[2]); r[7] = f2bf(f1[3]);
    *(ushort8*)(Ap + (size_t)m * 768 + k0) = r;
}

// ---------------------------------------------------------------
// Pack proj_w (D, C*P*P) fp32 -> bf16 (same layout = B^T)
// ---------------------------------------------------------------
__global__ __launch_bounds__(256) void pack_w(const float* __restrict__ w,
                                              ushort_t* __restrict__ Wp) {
    size_t g = ((size_t)blockIdx.x * 256 + threadIdx.x) * 8;
    f32x4 f0 = *(const f32x4*)(w + g);
    f32x4 f1 = *(const f32x4*)(w + g + 4);
    ushort8 r;
    r[0] = f2bf(f0[0]); r[1] = f2bf(f0[1]); r[2] = f2bf(f0[2]); r[3] = f2bf(f0[3]);
    r[4] = f2bf(f1[0]); r[5] = f2bf(f1[1]); r[6] = f2bf(f1[2]); r[7] = f2bf(f1[3]);
    *(ushort8*)(Wp + g) = r;
}

// ---------------------------------------------------------------
// Box MLP: emb[b][t][o][d] = relu(relu(box/224 @ w1) @ w2) + cats[t][o][d]
// one block per (b,t)
// ---------------------------------------------------------------
__global__ __launch_bounds__(256) void box_mlp(const float* __restrict__ meta,
                                               const float* __restrict__ w1,
                                               const float* __restrict__ w2,
                                               const float* __restrict__ cats,
                                               float* __restrict__ emb) {
    int bt = blockIdx.x;
    int b = bt / 8, t = bt % 8;
    __shared__ float H[3][384];
    int tid = threadIdx.x;
    for (int idx = tid; idx < 3 * 384; idx += 256) {
        int o = idx / 384, j = idx % 384;
        const float* mp = meta + ((b * 3 + o) * 8 + t) * 4;
        float s = 0.f;
        #pragma unroll
        for (int i = 0; i < 4; ++i) s += (mp[i] * (1.0f / 224.0f)) * w1[i * 384 + j];
        H[o][j] = fmaxf(s, 0.f);
    }
    __syncthreads();
    float acc[3][3] = {};
    for (int j = 0; j < 384; ++j) {
        float w0 = w2[j * 768 + tid];
        float w1v = w2[j * 768 + tid + 256];
        float w2v = w2[j * 768 + tid + 512];
        #pragma unroll
        for (int o = 0; o < 3; ++o) {
            float h = H[o][j];
            acc[o][0] += h * w0;
            acc[o][1] += h * w1v;
            acc[o][2] += h * w2v;
        }
    }
    #pragma unroll
    for (int o = 0; o < 3; ++o)
        #pragma unroll
        for (int c = 0; c < 3; ++c) {
            int d = tid + c * 256;
            emb[((size_t)(b * 8 + t) * 3 + o) * 768 + d] =
                fmaxf(acc[o][c], 0.f) + cats[(t * 3 + o) * 768 + d];
        }
}

// ---------------------------------------------------------------
// GEMM: C[m][n] = sum_k A[m][k] * Bt[n][k] + pb[n]
// 128x128 tile, BK=64, 4 waves (2x2), mfma_f32_16x16x32_bf16
// C stored (M, N) fp32 = feat in (bt, y, x, d) layout
// ---------------------------------------------------------------
__global__ __launch_bounds__(256) void gemm_bt(const ushort_t* __restrict__ A,
                                               const ushort_t* __restrict__ Bt,
                                               const float* __restrict__ pb,
                                               float* __restrict__ C) {
    __shared__ ushort_t lA[128 * 64];
    __shared__ ushort_t lB[128 * 64];
    int tid = threadIdx.x;
    int bm = blockIdx.x % 196;
    int bn = blockIdx.x / 196;
    size_t m0 = (size_t)bm * 128, n0 = (size_t)bn * 128;
    int w = tid >> 6, lane = tid & 63;
    int wr = w >> 1, wc = w & 1;

    f32x4 acc[4][4] = {};

    for (int kt = 0; kt < 12; ++kt) {
        int k0 = kt * 64;
        __syncthreads();
        #pragma unroll
        for (int r = 0; r < 4; ++r) {
            int cidx = r * 256 + tid;
            int row = cidx >> 3;
            int col = (cidx & 7) * 8;
            load_lds16(A + ((m0 + row) * 768 + k0 + col), &lA[(size_t)cidx * 8]);
        }
        #pragma unroll
        for (int r = 0; r < 4; ++r) {
            int cidx = r * 256 + tid;
            int row = cidx >> 3;
            int col = (cidx & 7) * 8;
            load_lds16(Bt + ((n0 + row) * 768 + k0 + col), &lB[(size_t)cidx * 8]);
        }
        __syncthreads();
        #pragma unroll
        for (int kk = 0; kk < 2; ++kk) {
            bf16x8 af[4], bfr[4];
            #pragma unroll
            for (int mi = 0; mi < 4; ++mi)
                af[mi] = *(const bf16x8*)&lA[(wr * 64 + mi * 16 + (lane & 15)) * 64
                                             + kk * 32 + (lane >> 4) * 8];
            #pragma unroll
            for (int ni = 0; ni < 4; ++ni)
                bfr[ni] = *(const bf16x8*)&lB[(wc * 64 + ni * 16 + (lane & 15)) * 64
                                              + kk * 32 + (lane >> 4) * 8];
            #pragma unroll
            for (int mi = 0; mi < 4; ++mi)
                #pragma unroll
                for (int ni = 0; ni < 4; ++ni)
                    acc[mi][ni] = __builtin_amdgcn_mfma_f32_16x16x32_bf16(
                        af[mi], bfr[ni], acc[mi][ni], 0, 0, 0);
        }
    }

    int rbase = (lane >> 4) * 4;
    int cl = lane & 15;
    #pragma unroll
    for (int ni = 0; ni < 4; ++ni) {
        size_t col = n0 + wc * 64 + ni * 16 + cl;
        float pbv = pb[col];
        #pragma unroll
        for (int mi = 0; mi < 4; ++mi) {
            size_t row = m0 + wr * 64 + mi * 16 + rbase;
            #pragma unroll
            for (int j = 0; j < 4; ++j) {
                C[(row + j) * 768 + col] = acc[mi][ni][j] + pbv;
            }
        }
    }
}

// ---------------------------------------------------------------
// ROI bilinear crop + emb add + final layout
// out[(b*3+o)][t][i*7+j][d] ; one block per (b,t,o,i), 192 threads (d0=tid*4)
// ---------------------------------------------------------------
__global__ __launch_bounds__(192) void roi_kernel(const float* __restrict__ meta,
                                                  const float* __restrict__ feat,
                                                  const float* __restrict__ emb,
                                                  float* __restrict__ out) {
    int id = blockIdx.x;
    int i = id % 7; id /= 7;
    int o = id % 3; id /= 3;
    int t = id % 8;
    int b = id / 8;

    const float* mp = meta + ((b * 3 + o) * 8 + t) * 4;
    float x1 = mp[0] * (1.f / 16.f);
    float y1 = mp[1] * (1.f / 16.f);
    float x2 = mp[2] * (1.f / 16.f);
    float y2 = mp[3] * (1.f / 16.f);

    float ci = (i + 0.5f) * (1.f / 7.f);
    float yg = y1 + ci * (y2 - y1) - 0.5f;
    float y0f = floorf(yg);
    float wy = yg - y0f;
    int y0 = min(max((int)y0f, 0), 13);
    int y1c = min(y0 + 1, 13);

    int bt = b * 8 + t;
    const float* fbase = feat + (size_t)bt * 196 * 768;
    const float* ep = emb + ((size_t)(b * 8 + t) * 3 + o) * 768;

    int d = threadIdx.x * 4;
    f32x4 ev = *(const f32x4*)(ep + d);

    for (int j = 0; j < 7; ++j) {
        float cj = (j + 0.5f) * (1.f / 7.f);
        float xgv = x1 + cj * (x2 - x1) - 0.5f;
        float x0f = floorf(xgv);
        float wx = xgv - x0f;
        int x0 = min(max((int)x0f, 0), 13);
        int x1i = min(x0 + 1, 13);

        f32x4 v00 = *(const f32x4*)(fbase + ((size_t)y0 * 14 + x0) * 768 + d);
        f32x4 v01 = *(const f32x4*)(fbase + ((size_t)y0 * 14 + x1i) * 768 + d);
        f32x4 v10 = *(const f32x4*)(fbase + ((size_t)y1c * 14 + x0) * 768 + d);
        f32x4 v11 = *(const f32x4*)(fbase + ((size_t)y1c * 14 + x1i) * 768 + d);

        float w00 = (1.f - wy) * (1.f - wx);
        float w01 = (1.f - wy) * wx;
        float w10 = wy * (1.f - wx);
        float w11 = wy * wx;

        f32x4 r;
        #pragma unroll
        for (int e = 0; e < 4; ++e)
            r[e] = v00[e] * w00 + v01[e] * w01 + v10[e] * w10 + v11[e] * w11 + ev[e];

        int pp = i * 7 + j;
        *(f32x4*)(out + ((((size_t)(b * 3 + o) * 8 + t) * 49 + pp) * 768 + d)) = r;
    }
}

extern "C" void kernel_launch(void* const* d_in, const int* in_sizes, int n_in,
                              void* d_out, int out_size, void* d_ws, size_t ws_size,
                              hipStream_t stream) {
    const float* x     = (const float*)d_in[0];
    const float* meta  = (const float*)d_in[1];
    const float* projw = (const float*)d_in[2];
    const float* projb = (const float*)d_in[3];
    const float* cats  = (const float*)d_in[4];
    const float* w1    = (const float*)d_in[5];
    const float* w2    = (const float*)d_in[6];
    float* out = (float*)d_out;

    char* ws = (char*)d_ws;
    // workspace layout (bytes)
    const size_t szA   = (size_t)GM * GK * 2;        // 38,535,168
    const size_t szW   = (size_t)GN * GK * 2;        //  1,179,648
    const size_t szF   = (size_t)GM * GN * 4;        // 77,070,336
    ushort_t* Ap  = (ushort_t*)(ws);
    ushort_t* Wp  = (ushort_t*)(ws + szA);
    float*    feat = (float*)(ws + szA + szW);
    float*    emb  = (float*)(ws + szA + szW + szF);

    // 1) pack A: (M*K/8)/256 = 9408 blocks
    pack_a<<<9408, 256, 0, stream>>>(x, Ap);
    // 2) pack W: (768*768/8)/256 = 288 blocks
    pack_w<<<288, 256, 0, stream>>>(projw, Wp);
    // 3) box MLP: one block per (b,t)
    box_mlp<<<128, 256, 0, stream>>>(meta, w1, w2, cats, emb);
    // 4) GEMM: 196 * 6 tiles
    gemm_bt<<<196 * 6, 256, 0, stream>>>(Ap, Wp, projb, feat);
    // 5) ROI: one block per (b,t,o,i)
    roi_kernel<<<16 * 8 * 3 * 7, 192, 0, stream>>>(meta, feat, emb, out);
}